// Round 1
// baseline (1072.543 us; speedup 1.0000x reference)
//
#include <hip/hip_runtime.h>
#include <math.h>

#define N_ROWS 65536
#define CB 1024
#define SPLITS 4
#define JS (CB / SPLITS)   // 256 codebook entries per split

// ---------------------------------------------------------------------------
// Exact emulation of numpy's pairwise_sum for n=64 fp32 (AVX-512 path):
//   r0..r3 = 16-lane vector loads; sum = (r0+r1)+(r2+r3);
//   then _mm512_reduce_add_ps tree: fold at lane distance 8, 4, 2, 1.
// fp contract OFF so the squares are not fused into the adds (hipcc default
// is -ffp-contract=fast which would change the rounding vs numpy).
// ---------------------------------------------------------------------------
__device__ __forceinline__ float tree_sum64_sq(const float* x) {
#pragma clang fp contract(off)
    float sq[64];
#pragma unroll
    for (int i = 0; i < 64; ++i) sq[i] = x[i] * x[i];
    float s[16];
#pragma unroll
    for (int l = 0; l < 16; ++l) s[l] = (sq[l] + sq[l + 16]) + (sq[l + 32] + sq[l + 48]);
    float t[8];
#pragma unroll
    for (int l = 0; l < 8; ++l) t[l] = s[l] + s[l + 8];
    float u[4];
#pragma unroll
    for (int l = 0; l < 4; ++l) u[l] = t[l] + t[l + 4];
    float v0 = u[0] + u[2];
    float v1 = u[1] + u[3];
    return v0 + v1;
}

// sorted-triple insert, strict < (ties keep earlier-inserted = lower index,
// matching jax.lax.top_k / stable argsort tie-breaking when fed in ascending
// index order)
__device__ __forceinline__ void top3_insert(float d, int j,
                                            float& v0, float& v1, float& v2,
                                            int& i0, int& i1, int& i2) {
    bool b0 = d < v0, b1 = d < v1, b2 = d < v2;
    v2 = b1 ? v1 : (b2 ? d : v2);
    i2 = b1 ? i1 : (b2 ? j : i2);
    v1 = b0 ? v0 : (b1 ? d : v1);
    i1 = b0 ? i0 : (b1 ? j : i1);
    v0 = b0 ? d : v0;
    i0 = b0 ? j : i0;
}

// ---------------------------------------------------------------------------
// B[j] = np.sum(emb[j]**2)  (exact tree emulation)
// ---------------------------------------------------------------------------
__global__ __launch_bounds__(256) void embB_kernel(const float* __restrict__ emb,
                                                   float* __restrict__ B) {
    int j = blockIdx.x * 256 + threadIdx.x;
    if (j >= CB) return;
    float e[64];
    const float4* e4 = (const float4*)(emb + (size_t)j * 64);
#pragma unroll
    for (int k = 0; k < 16; ++k) {
        float4 v = e4[k];
        e[4 * k] = v.x; e[4 * k + 1] = v.y; e[4 * k + 2] = v.z; e[4 * k + 3] = v.w;
    }
    B[j] = tree_sum64_sq(e);
}

// ---------------------------------------------------------------------------
// Scoring: one thread per z-row, 4-way split over codebook entries.
// d_ij = fl(fl(A_i + B_j) - 2*C_ij), C accumulated by strict ascending-k fmaf
// (emulating the single-accumulator sequential-k FMA of BLAS sgemm).
// Partial top-3 per (row, split) written to scratch (carved from out3 region,
// which is overwritten later by the one-hot kernel).
// ---------------------------------------------------------------------------
__global__ __launch_bounds__(256) void score_kernel(const float* __restrict__ z,
                                                    const float* __restrict__ emb,
                                                    const float* __restrict__ B,
                                                    float* __restrict__ scrD,
                                                    int* __restrict__ scrI) {
    int bid = blockIdx.x;
    int split = bid & (SPLITS - 1);
    int rowBlk = bid >> 2;
    int row = rowBlk * 256 + threadIdx.x;

    float zr[64];
    const float4* z4 = (const float4*)(z + (size_t)row * 64);
#pragma unroll
    for (int k = 0; k < 16; ++k) {
        float4 v = z4[k];
        zr[4 * k] = v.x; zr[4 * k + 1] = v.y; zr[4 * k + 2] = v.z; zr[4 * k + 3] = v.w;
    }
    float A = tree_sum64_sq(zr);

    float v0 = 3.402823466e38f, v1 = 3.402823466e38f, v2 = 3.402823466e38f;
    int i0 = 0, i1 = 0, i2 = 0;
    int jbase = split * JS;

    for (int jj = 0; jj < JS; ++jj) {
        int j = jbase + jj;                       // uniform across the wave
        const float4* e4 = (const float4*)(emb + (size_t)j * 64);
        float Bj = B[j];                          // uniform -> scalar load
        float acc = 0.0f;
#pragma unroll
        for (int k = 0; k < 16; ++k) {
            float4 e = e4[k];                     // uniform -> scalar loads
            acc = fmaf(zr[4 * k],     e.x, acc);
            acc = fmaf(zr[4 * k + 1], e.y, acc);
            acc = fmaf(zr[4 * k + 2], e.z, acc);
            acc = fmaf(zr[4 * k + 3], e.w, acc);
        }
        float d = (A + Bj) - 2.0f * acc;          // fma-contraction here is
                                                  // bit-identical (2*acc exact)
        top3_insert(d, j, v0, v1, v2, i0, i1, i2);
    }
    size_t o = ((size_t)split * N_ROWS + row) * 3;
    scrD[o] = v0; scrD[o + 1] = v1; scrD[o + 2] = v2;
    scrI[o] = i0; scrI[o + 1] = i1; scrI[o + 2] = i2;
}

// ---------------------------------------------------------------------------
// Merge the 4 split-partials (splits in ascending index order -> strict-<
// insert keeps lower index on ties), then do the whole per-row epilogue:
// topk_idx (as float), z_q_st, histogram for perplexity, loss partial sum.
// ---------------------------------------------------------------------------
__global__ __launch_bounds__(256) void merge_kernel(const float* __restrict__ z,
                                                    const float* __restrict__ emb,
                                                    const float* __restrict__ scrD,
                                                    const int* __restrict__ scrI,
                                                    float* __restrict__ out0,
                                                    float* __restrict__ out4,
                                                    int* __restrict__ hist,
                                                    float* __restrict__ lossAcc) {
    int row = blockIdx.x * 256 + threadIdx.x;

    float v0 = 3.402823466e38f, v1 = 3.402823466e38f, v2 = 3.402823466e38f;
    int i0 = 0, i1 = 0, i2 = 0;
#pragma unroll
    for (int s = 0; s < SPLITS; ++s) {
        size_t o = ((size_t)s * N_ROWS + row) * 3;
#pragma unroll
        for (int t = 0; t < 3; ++t) {
            float d = scrD[o + t];
            int j = scrI[o + t];
            top3_insert(d, j, v0, v1, v2, i0, i1, i2);
        }
    }

    const float* e0 = emb + (size_t)i0 * 64;
    const float* e1 = emb + (size_t)i1 * 64;
    const float* e2 = emb + (size_t)i2 * 64;
    const float4* z4 = (const float4*)(z + (size_t)row * 64);
    float4* o4 = (float4*)(out0 + (size_t)row * 64);

    float lsum = 0.0f;
#pragma unroll
    for (int k4 = 0; k4 < 16; ++k4) {
        float4 zv = z4[k4];
        float4 st;
        {
            int k = 4 * k4;
            float zq = ((e0[k] + e1[k]) + e2[k]) / 3.0f;   // np.mean over 3
            float df = zq - zv.x;
            st.x = zv.x + df;                               // straight-through
            lsum = fmaf(df, df, lsum);
        }
        {
            int k = 4 * k4 + 1;
            float zq = ((e0[k] + e1[k]) + e2[k]) / 3.0f;
            float df = zq - zv.y;
            st.y = zv.y + df;
            lsum = fmaf(df, df, lsum);
        }
        {
            int k = 4 * k4 + 2;
            float zq = ((e0[k] + e1[k]) + e2[k]) / 3.0f;
            float df = zq - zv.z;
            st.z = zv.z + df;
            lsum = fmaf(df, df, lsum);
        }
        {
            int k = 4 * k4 + 3;
            float zq = ((e0[k] + e1[k]) + e2[k]) / 3.0f;
            float df = zq - zv.w;
            st.w = zv.w + df;
            lsum = fmaf(df, df, lsum);
        }
        o4[k4] = st;
    }

    size_t ob = (size_t)row * 3;
    out4[ob]     = (float)i0;
    out4[ob + 1] = (float)i1;
    out4[ob + 2] = (float)i2;
    atomicAdd(&hist[i0], 1);
    atomicAdd(&hist[i1], 1);
    atomicAdd(&hist[i2], 1);

    // wave-level reduce of loss partial, one atomic per wave
#pragma unroll
    for (int off = 32; off >= 1; off >>= 1) lsum += __shfl_down(lsum, off);
    if ((threadIdx.x & 63) == 0) atomicAdd(lossAcc, lsum);
}

// ---------------------------------------------------------------------------
// Fused zero + one-hot fill of the 805 MB encodings output.
// One float4 per thread, fully coalesced.
// ---------------------------------------------------------------------------
__global__ __launch_bounds__(256) void onehot_kernel(const float* __restrict__ idxf,
                                                     float4* __restrict__ out3) {
    size_t q = (size_t)blockIdx.x * 256 + threadIdx.x;   // float4 index
    int slice = (int)(q >> 8);                            // 256 float4 per row of 1024
    int c0 = (int)(q & 255) * 4;
    int idx = (int)idxf[slice];
    float4 v;
    v.x = (c0     == idx) ? 1.0f : 0.0f;
    v.y = (c0 + 1 == idx) ? 1.0f : 0.0f;
    v.z = (c0 + 2 == idx) ? 1.0f : 0.0f;
    v.w = (c0 + 3 == idx) ? 1.0f : 0.0f;
    out3[q] = v;
}

// ---------------------------------------------------------------------------
// Perplexity from histogram + loss finalize.
// ---------------------------------------------------------------------------
__global__ __launch_bounds__(256) void finalize_kernel(const int* __restrict__ hist,
                                                       const float* __restrict__ lossAcc,
                                                       float* __restrict__ out1,
                                                       float* __restrict__ out2) {
    __shared__ float red[256];
    int t = threadIdx.x;
    float local = 0.0f;
    for (int b = t; b < CB; b += 256) {
        float em = (float)hist[b] / 196608.0f;
        local += em * logf(em + 1e-10f);
    }
    red[t] = local;
    __syncthreads();
    for (int s = 128; s >= 1; s >>= 1) {
        if (t < s) red[t] += red[t + s];
        __syncthreads();
    }
    if (t == 0) {
        *out2 = expf(-red[0]);
        float m = *lossAcc / 4194304.0f;
        *out1 = 0.25f * m + m;     // BETA_C*mse + mse (stop_gradient = identity fwd)
    }
}

extern "C" void kernel_launch(void* const* d_in, const int* in_sizes, int n_in,
                              void* d_out, int out_size, void* d_ws, size_t ws_size,
                              hipStream_t stream) {
    const float* z   = (const float*)d_in[0];   // [16,64,64,64] -> 65536 x 64
    const float* emb = (const float*)d_in[1];   // [1024, 64]

    float* out  = (float*)d_out;
    float* out0 = out;                                    // z_q_st  4194304
    float* out1 = out + 4194304;                          // loss    1
    float* out2 = out + 4194305;                          // perplexity 1
    float* out3 = out + 4194306;                          // encodings 201326592
    float* out4 = out + 4194306 + 201326592ll;            // topk_idx (as float) 196608

    int*   hist    = (int*)d_ws;                          // 1024 ints @ 0
    float* lossAcc = (float*)((char*)d_ws + 4096);        // 1 float
    float* B       = (float*)((char*)d_ws + 8192);        // 1024 floats

    // scratch for split-partial top3, carved from the out3 region (rewritten
    // later by onehot_kernel): 4*65536*3 floats + same ints = 6.3 MB
    float* scrD = out3;
    int*   scrI = (int*)(out3 + (size_t)SPLITS * N_ROWS * 3);

    hipMemsetAsync(d_ws, 0, 4096 + 16, stream);           // hist + lossAcc

    embB_kernel<<<4, 256, 0, stream>>>(emb, B);
    score_kernel<<<(N_ROWS / 256) * SPLITS, 256, 0, stream>>>(z, emb, B, scrD, scrI);
    merge_kernel<<<N_ROWS / 256, 256, 0, stream>>>(z, emb, scrD, scrI, out0, out4,
                                                   hist, lossAcc);
    onehot_kernel<<<196608, 256, 0, stream>>>(out4, (float4*)out3);
    finalize_kernel<<<1, 256, 0, stream>>>(hist, lossAcc, out1, out2);
}